// Round 5
// baseline (747.974 us; speedup 1.0000x reference)
//
#include <hip/hip_runtime.h>
#include <math.h>

// FORCE / RLS, round 8: communication-shape experiment — 32 fat worker blocks
// (bit-identical math), plain-asm sc0/sc1 publishes, heaters removed.
//
// Eliminated so far: barrier structure (r4), ordering (r5 dataflow), compute/
// LDS (r6), poll shape (r6), clocks (r7: heaters raised VALUBusy 2.8->11.5%
// and time got WORSE). Remaining variables: producer count, per-line reader
// fan-in, line count, and store-lowering (atomic store might emit an RMW).
// This round halves producers+fan-in+lines in one controlled step:
//   NBLK 64->32, JPB 16->32. Bit-identicality is preserved by keeping the
//   old reduction trees: each thread computes TWO of the 16 q-partials
//   (redM/redK stay [16][JPB]), and each block publishes TWO old-style
//   16-column gpart partials (gpart[t][2b], gpart[t][2b+1]) so the consumer
//   gather order is byte-for-byte the round-6 order. Publishes use explicit
//   `global_store_dword ... sc0 sc1` (plain store, never an RMW).
//
// Implicit-P math (P0 = I, wO0 = 0), bit-identical to rounds 3..7:
//   k_t = h_t - sum_{s<t} d_s k_s,  g_s = k_s . h_t,  d_s = c_s g_s
//   c_t = 1/(1 + h.h - sum d_s g_s), z_t = -sum_{s<t} d_s e_s, e_t = z_t - y_t

#define NN   1024
#define TT   128
#define IDIM 16
#define ODIM 8
#define NBLK 32              // worker blocks (was 64)
#define OCOL 64              // old-style gpart columns: 2 per block, layout kept
#define NTHR 256
#define JPB  32              // columns per block (was 16)
#define SENT 0xFFFFFFFFu

#define AL(p)    __hip_atomic_load((p), __ATOMIC_RELAXED, __HIP_MEMORY_SCOPE_AGENT)

struct WS {
  float h[TT][NN];             // 512 KB, sentinel-initialized, written once
  float gpart[TT][OCOL][TT];   // 4 MB,   sentinel-initialized, written once
};

// Agent-coherent 16B load (bypass L1+L2 so we never spin on a stale line).
__device__ __forceinline__ float4 llc_load4(const float4* p) {
  float4 v;
  asm volatile("global_load_dwordx4 %0, %1, off sc0 sc1\n\t"
               "s_waitcnt vmcnt(0)"
               : "=v"(v) : "v"(p) : "memory");
  return v;
}

// Agent-coherent plain 4B store (guaranteed NOT an RMW).
__device__ __forceinline__ void llc_store(float* p, float v) {
  asm volatile("global_store_dword %0, %1, off sc0 sc1"
               :: "v"(p), "v"(v) : "memory");
}

// ~32 dependent FMAs (~50ns): busy backoff between retry rounds.
__device__ __forceinline__ void spin_pause() {
  float a = 1.0f;
#pragma unroll
  for (int i = 0; i < 32; ++i) a = __builtin_fmaf(a, 1.0000001f, 1.0f);
  asm volatile("" :: "v"(a));   // keep the chain alive, no memory traffic
}

__global__ __launch_bounds__(NTHR, 1) void force_rls_kernel(
    const float* __restrict__ x, const float* __restrict__ y,
    const float* __restrict__ Win, const float* __restrict__ Wrec,
    const float* __restrict__ Wfb, float* __restrict__ out, WS* ws)
{
  const int tid  = threadIdx.x;
  const int bid  = blockIdx.x;
  const int lane = tid & 63;
  const int wv   = tid >> 6;
  const int j0   = bid * JPB;
  const int jj   = tid & 31;    // column within block
  const int qq   = tid >> 5;    // 0..7: owns q-partials qq and qq+8
  const int sF   = tid & 127;   // slot index for the g reduction
  const int hf   = tid >> 7;    // which half of the 64 old-columns to sum

  __shared__ float Ksl[TT][JPB];
  __shared__ float XW[TT][JPB];
  __shared__ float Ybuf[TT][ODIM];
  __shared__ float Ebuf[TT][ODIM];
  __shared__ float hfull[NN];
  __shared__ float cbuf[TT], dbuf[TT];
  __shared__ float Wfb_s[ODIM][JPB];
  __shared__ float Winsl[IDIM][JPB];
  __shared__ float redK[16][JPB], redM[16][JPB];
  __shared__ float redG[2][TT];
  __shared__ float hcb[JPB], abuf[JPB], zbuf[ODIM];
  __shared__ float red2[4];
  __shared__ float sHH;

  // ---------------- init ----------------
  // Wrec slice -> registers. Thread (qq,jj) owns the OLD q-partials q=qq and
  // q=qq+8 of column j0+jj: rows r = 64i + 4q + c, i=0..15.
  float4 wA[16], wB[16];
  {
    const int col = j0 + jj;
#pragma unroll
    for (int i = 0; i < 16; ++i) {
      const int rA = (i << 6) + (qq << 2);          // q = qq
      wA[i].x = Wrec[(size_t)(rA + 0) * NN + col];
      wA[i].y = Wrec[(size_t)(rA + 1) * NN + col];
      wA[i].z = Wrec[(size_t)(rA + 2) * NN + col];
      wA[i].w = Wrec[(size_t)(rA + 3) * NN + col];
      const int rB = rA + 32;                        // q = qq + 8
      wB[i].x = Wrec[(size_t)(rB + 0) * NN + col];
      wB[i].y = Wrec[(size_t)(rB + 1) * NN + col];
      wB[i].z = Wrec[(size_t)(rB + 2) * NN + col];
      wB[i].w = Wrec[(size_t)(rB + 3) * NN + col];
    }
  }
#pragma unroll
  for (int m = 0; m < (IDIM * JPB) / NTHR; ++m) {   // 2 iters
    int e = m * NTHR + tid; int i = e >> 5, j = e & 31;
    Winsl[i][j] = Win[i * NN + j0 + j];
  }
  { int o = tid >> 5, j = tid & 31; Wfb_s[o][j] = Wfb[o * NN + j0 + j]; }
  for (int m = 0; m < (TT * ODIM) / NTHR; ++m) {
    int e = m * NTHR + tid; Ybuf[e >> 3][e & 7] = y[e];
  }
  if (tid < JPB) abuf[tid] = 0.f;
  if (tid < ODIM) zbuf[tid] = 0.f;
  __syncthreads();
  for (int m = 0; m < (TT * JPB) / NTHR; ++m) {     // 16 iters
    int e = m * NTHR + tid; int t = e >> 5, j = e & 31;
    float s = 0.f;
#pragma unroll
    for (int i = 0; i < IDIM; ++i) s += x[t * IDIM + i] * Winsl[i][j];
    XW[t][j] = s;
  }
  __syncthreads();

  // ---------------- main loop: NO grid barrier, dataflow only ----------------
  for (int t = 0; t < TT; ++t) {
    // [A] gather h_{t-1} and g-partials of step t-1, spin-until-valid.
    //     Spin order: gpart FIRST (published after h by every producer).
    if (t >= 1) {
      float gv[32];
      const float* gq = &ws->gpart[t - 1][hf * 32][0] + sF;
      if (sF < t) {
#pragma unroll
        for (int b = 0; b < 32; ++b) gv[b] = AL(gq + b * TT);
      }
      const float4* hp = (const float4*)ws->h[t - 1] + tid;
      float4 hv = llc_load4(hp);   // vmcnt(0) also completes the gv loads
      float ga = 0.f;
      if (sF < t) {
        for (;;) {
          bool bad = false;
#pragma unroll
          for (int b = 0; b < 32; ++b) bad |= (__float_as_uint(gv[b]) == SENT);
          if (!bad) break;
          spin_pause();
#pragma unroll
          for (int b = 0; b < 32; ++b)
            if (__float_as_uint(gv[b]) == SENT) gv[b] = AL(gq + b * TT);
        }
#pragma unroll
        for (int b = 0; b < 32; ++b) ga += gv[b];   // same order as rounds 5-7
      }
      while (__float_as_uint(hv.x) == SENT || __float_as_uint(hv.y) == SENT ||
             __float_as_uint(hv.z) == SENT || __float_as_uint(hv.w) == SENT) {
        spin_pause();
        hv = llc_load4(hp);
      }
      ((float4*)hfull)[tid] = hv;
      redG[hf][sF] = ga;                  // 0 for sF >= t (never read there)
    }
    __syncthreads();

    // [C1] matvec partials from REGISTER W: two old q-partials per thread,
    //      each with its own accumulator and the old i-ascending order.
    float mpA = 0.f, mpB = 0.f;
    if (t >= 1) {
      const float4* hf4 = (const float4*)hfull;
#pragma unroll
      for (int i = 0; i < 16; ++i) {
        const int rbA = (i << 6) + (qq << 2);
        const float4 hv = hf4[rbA >> 2];
        mpA += hv.x * wA[i].x + hv.y * wA[i].y + hv.z * wA[i].z + hv.w * wA[i].w;
      }
#pragma unroll
      for (int i = 0; i < 16; ++i) {
        const int rbB = (i << 6) + 32 + (qq << 2);
        const float4 hv = hf4[rbB >> 2];
        mpB += hv.x * wB[i].x + hv.y * wB[i].y + hv.z * wB[i].z + hv.w * wB[i].w;
      }
    }
    redM[qq][jj] = mpA;
    redM[qq + 8][jj] = mpB;

    // [F1] deferred reduce of step t-1: g_s, d_s, ||h||^2, Sigma d*g
    float dval = 0.f, gval = 0.f;
    if (t >= 1 && tid <= t - 1) {
      float g = redG[0][tid] + redG[1][tid];
      gval = g;
      if (tid < t - 1) { dval = cbuf[tid] * g; dbuf[tid] = dval; }
      else sHH = g;
    }
    float s1p = dval * gval;
    s1p += __shfl_xor(s1p, 1, 64);
    s1p += __shfl_xor(s1p, 2, 64);
    s1p += __shfl_xor(s1p, 4, 64);
    s1p += __shfl_xor(s1p, 8, 64);
    s1p += __shfl_xor(s1p, 16, 64);
    s1p += __shfl_xor(s1p, 32, 64);
    if (lane == 0) red2[wv] = s1p;
    __syncthreads();

    // [F2] c_{t-1}, z_{t-1}, e_{t-1}   +   [B] K[t-1] partials
    if (t >= 1) {
      if (tid == 0) {
        float s1 = red2[0] + red2[1] + red2[2] + red2[3];
        cbuf[t - 1] = 1.f / (1.f + sHH - s1);
      }
      if (wv == 0) {                      // z_{t-1} = -sum_{s<t-1} d_s e_s
        const int o = lane & 7, gr8 = lane >> 3;
        float zp = 0.f;
        for (int s = gr8; s < t - 1; s += 8) zp += dbuf[s] * Ebuf[s][o];
        zp += __shfl_xor(zp, 8, 64);
        zp += __shfl_xor(zp, 16, 64);
        zp += __shfl_xor(zp, 32, 64);
        if (lane < 8) {
          float z = -zp;
          zbuf[o] = z;
          Ebuf[t - 1][o] = z - Ybuf[t - 1][o];
          if (bid == 0) out[(t - 1) * ODIM + o] = z;
        }
      }
    }
    float kpA = 0.f, kpB = 0.f;
    if (t >= 2) {
      for (int s = qq; s < t - 1; s += 16) kpA -= dbuf[s] * Ksl[s][jj];
      for (int s = qq + 8; s < t - 1; s += 16) kpB -= dbuf[s] * Ksl[s][jj];
    }
    redK[qq][jj] = kpA;
    redK[qq + 8][jj] = kpB;
    __syncthreads();

    // [C2] combine -> a_t, h_t; finalize K[t-1]; publish h (fire-and-forget)
    if (tid < JPB) {
      const int j = tid;
      if (t >= 1) {
        float kv = hfull[j0 + j];
#pragma unroll
        for (int q = 0; q < 16; ++q) kv += redK[q][j];
        Ksl[t - 1][j] = kv;
      }
      float acc = 0.f;
#pragma unroll
      for (int q = 0; q < 16; ++q) acc += redM[q][j];
      float fb = 0.f;
#pragma unroll
      for (int o = 0; o < ODIM; ++o) fb += zbuf[o] * Wfb_s[o][j];
      float a = 0.9f * abuf[j] + 0.1f * (acc + XW[t][j] + fb);
      abuf[j] = a;
      float h = tanhf(a);
      hcb[j] = h;
      llc_store(&ws->h[t][j0 + j], h);
    }
    __syncthreads();

    // [D] publish TWO old-style 16-column g-partials (layout = rounds 5-7)
    if (tid <= t) {
      float gpA = 0.f, gpB = 0.f;
      if (tid < t) {
#pragma unroll
        for (int j = 0; j < 16; ++j) gpA += Ksl[tid][j] * hcb[j];
#pragma unroll
        for (int j = 16; j < 32; ++j) gpB += Ksl[tid][j] * hcb[j];
      } else {
#pragma unroll
        for (int j = 0; j < 16; ++j) gpA += hcb[j] * hcb[j];
#pragma unroll
        for (int j = 16; j < 32; ++j) gpB += hcb[j] * hcb[j];
      }
      llc_store(&ws->gpart[t][2 * bid][tid], gpA);
      llc_store(&ws->gpart[t][2 * bid + 1][tid], gpB);
    }
    // no drain, no flag, no barrier — consumers validate per-word
  }

  // ---------------- epilogue: z_127 -> out[127] (bid 0 only) ----------------
  if (bid == 0) {
    float ga = 0.f;
    if (sF < TT - 1) {
      const float* gq = &ws->gpart[TT - 1][hf * 32][0] + sF;
      float gv[32];
#pragma unroll
      for (int b = 0; b < 32; ++b) gv[b] = AL(gq + b * TT);
      for (;;) {
        bool bad = false;
#pragma unroll
        for (int b = 0; b < 32; ++b) bad |= (__float_as_uint(gv[b]) == SENT);
        if (!bad) break;
        spin_pause();
#pragma unroll
        for (int b = 0; b < 32; ++b)
          if (__float_as_uint(gv[b]) == SENT) gv[b] = AL(gq + b * TT);
      }
#pragma unroll
      for (int b = 0; b < 32; ++b) ga += gv[b];
    }
    redG[hf][sF] = ga;
    __syncthreads();
    if (tid < TT - 1) dbuf[tid] = cbuf[tid] * (redG[0][tid] + redG[1][tid]);
    __syncthreads();
    if (wv == 0) {
      const int o = lane & 7, gr8 = lane >> 3;
      float zp = 0.f;
      for (int s = gr8; s < TT - 1; s += 8) zp += dbuf[s] * Ebuf[s][o];
      zp += __shfl_xor(zp, 8, 64);
      zp += __shfl_xor(zp, 16, 64);
      zp += __shfl_xor(zp, 32, 64);
      if (lane < 8) out[(TT - 1) * ODIM + o] = -zp;
    }
  }
}

extern "C" void kernel_launch(void* const* d_in, const int* in_sizes, int n_in,
                              void* d_out, int out_size, void* d_ws, size_t ws_size,
                              hipStream_t stream) {
  const float* x    = (const float*)d_in[0];
  const float* y    = (const float*)d_in[1];
  const float* Win  = (const float*)d_in[2];
  const float* Wrec = (const float*)d_in[3];
  const float* Wfb  = (const float*)d_in[4];
  // d_in[5] = wO (zeros), d_in[6] = P (identity): folded into implicit-P math.
  float* out = (float*)d_out;
  WS* ws = (WS*)d_ws;

  // Sentinel-fill the once-written dataflow buffers (0xFF bytes = NaN words).
  hipMemsetAsync(d_ws, 0xFF, sizeof(WS), stream);
  force_rls_kernel<<<NBLK, NTHR, 0, stream>>>(x, y, Win, Wrec, Wfb, out, ws);
}

// Round 9
// 671.222 us; speedup vs baseline: 1.1143x; 1.1143x over previous
//
#include <hip/hip_runtime.h>
#include <math.h>

// FORCE / RLS, round 12: r6 base (best verified: 623us dispatch, absmax
// 0.015625) + MERGED single-spin gather.
//
// r9-r11 (XCD clustering) abandoned: the intra-XCD plain-store/sc0-load
// protocol fails on HW (r11: flags/data not visible -> dead-latch free-run,
// absmax 4e11). Verified transport = agent-scope sc0+sc1 dataflow (r5/r6).
//
// Remaining reducible cost found by audit of r6's consumer: the gpart spin
// runs to completion BEFORE h is re-checked, so an h retry costs one extra
// serialized LLC RT, and the two spins can't share retry rounds. This round:
// issue gv + h together; one retry loop re-issues only invalid words; ONE
// vmcnt(0) per round (+ sched_barrier(0) so register-only sentinel checks
// can't hoist above the wait -- guide rule #18).
//
// Everything else byte-identical to r6: same reduction orders, same publish
// order (h at C2, gpart at D), same spin_pause backoff.
//
// Implicit-P math (P0 = I, wO0 = 0):
//   k_t = h_t - sum_{s<t} d_s k_s,  g_s = k_s . h_t,  d_s = c_s g_s
//   c_t = 1/(1 + h.h - sum d_s g_s), z_t = -sum_{s<t} d_s e_s, e_t = z_t - y_t

#define NN   1024
#define TT   128
#define IDIM 16
#define ODIM 8
#define NBLK 64
#define NTHR 256
#define JPB  16
#define SENT 0xFFFFFFFFu

#define AL(p)    __hip_atomic_load((p), __ATOMIC_RELAXED, __HIP_MEMORY_SCOPE_AGENT)
#define AS(p, v) __hip_atomic_store((p), (v), __ATOMIC_RELAXED, __HIP_MEMORY_SCOPE_AGENT)

struct WS {
  float h[TT][NN];             // 512 KB, sentinel-initialized, written once
  float gpart[TT][NBLK][TT];   // 4 MB,   sentinel-initialized, written once
};

// Agent-coherent async loads (bypass L1+L2; caller issues vmcnt wait).
__device__ __forceinline__ float llc_load_async(const float* p) {
  float v;
  asm volatile("global_load_dword %0, %1, off sc0 sc1"
               : "=v"(v) : "v"(p) : "memory");
  return v;
}
__device__ __forceinline__ float4 llc_load4_async(const float4* p) {
  float4 v;
  asm volatile("global_load_dwordx4 %0, %1, off sc0 sc1"
               : "=v"(v) : "v"(p) : "memory");
  return v;
}
__device__ __forceinline__ void vm_wait0() {
  asm volatile("s_waitcnt vmcnt(0)" ::: "memory");
  __builtin_amdgcn_sched_barrier(0);   // rule #18: pin the following checks
}

// ~32 dependent FMAs (~50ns): busy backoff between retry rounds.
__device__ __forceinline__ void spin_pause() {
  float a = 1.0f;
#pragma unroll
  for (int i = 0; i < 32; ++i) a = __builtin_fmaf(a, 1.0000001f, 1.0f);
  asm volatile("" :: "v"(a));   // keep the chain alive, no memory traffic
}

__device__ __forceinline__ int is_sent(float v) {
  return __float_as_uint(v) == SENT;
}

__global__ __launch_bounds__(NTHR, 1) void force_rls_kernel(
    const float* __restrict__ x, const float* __restrict__ y,
    const float* __restrict__ Win, const float* __restrict__ Wrec,
    const float* __restrict__ Wfb, float* __restrict__ out, WS* ws)
{
  const int tid  = threadIdx.x;
  const int bid  = blockIdx.x;
  const int lane = tid & 63;
  const int wv   = tid >> 6;
  const int j0   = bid * JPB;
  const int jj   = tid & 15;
  const int qq   = tid >> 4;
  const int sF   = tid & 127;   // slot index for the g reduction
  const int hf   = tid >> 7;    // which half of the 64 blocks this thread sums

  __shared__ float Ksl[TT][JPB];
  __shared__ float XW[TT][JPB];
  __shared__ float Ybuf[TT][ODIM];
  __shared__ float Ebuf[TT][ODIM];
  __shared__ float hfull[NN];
  __shared__ float cbuf[TT], dbuf[TT];
  __shared__ float Wfb_s[ODIM][JPB];
  __shared__ float Winsl[IDIM][JPB];
  __shared__ float redK[16][JPB], redM[16][JPB];
  __shared__ float redG[2][TT];
  __shared__ float hcb[JPB], abuf[JPB], zbuf[ODIM];
  __shared__ float red2[4];
  __shared__ float sHH;

  // ---------------- init ----------------
  // Wrec slice -> registers: thread (qq,jj) owns rows r = 64*i + 4*qq + c of
  // column j0+jj. Same element-to-lane mapping as r6.
  float4 w[16];
  {
    const int col = j0 + jj;
#pragma unroll
    for (int i = 0; i < 16; ++i) {
      const int r0 = (i << 6) + (qq << 2);
      w[i].x = Wrec[(size_t)(r0 + 0) * NN + col];
      w[i].y = Wrec[(size_t)(r0 + 1) * NN + col];
      w[i].z = Wrec[(size_t)(r0 + 2) * NN + col];
      w[i].w = Wrec[(size_t)(r0 + 3) * NN + col];
    }
  }
  { int i = tid >> 4, j = tid & 15; Winsl[i][j] = Win[i * NN + j0 + j]; }
  if (tid < ODIM * JPB) { int o = tid >> 4, j = tid & 15; Wfb_s[o][j] = Wfb[o * NN + j0 + j]; }
  for (int m = 0; m < (TT * ODIM) / NTHR; ++m) {
    int e = m * NTHR + tid; Ybuf[e >> 3][e & 7] = y[e];
  }
  if (tid < JPB) abuf[tid] = 0.f;
  if (tid < ODIM) zbuf[tid] = 0.f;
  __syncthreads();
  for (int m = 0; m < (TT * JPB) / NTHR; ++m) {
    int e = m * NTHR + tid; int t = e >> 4, j = e & 15;
    float s = 0.f;
#pragma unroll
    for (int i = 0; i < IDIM; ++i) s += x[t * IDIM + i] * Winsl[i][j];
    XW[t][j] = s;
  }
  __syncthreads();

  // ---------------- main loop: NO grid barrier, dataflow only ----------------
  for (int t = 0; t < TT; ++t) {
    // [A] MERGED spin: gather h_{t-1} and g-partials of step t-1 together.
    //     Every retry round re-issues only invalid words; one vmcnt/round.
    if (t >= 1) {
      const float* gq = &ws->gpart[t - 1][hf * 32][0] + sF;
      const float4* hp = (const float4*)ws->h[t - 1] + tid;
      const bool gneed = (sF < t);
      float gv[32];
      float4 hv;
      if (gneed) {
#pragma unroll
        for (int b = 0; b < 32; ++b) gv[b] = llc_load_async(gq + b * TT);
      }
      hv = llc_load4_async(hp);
      vm_wait0();
      for (;;) {
        bool hbad = is_sent(hv.x) || is_sent(hv.y) ||
                    is_sent(hv.z) || is_sent(hv.w);
        bool gbad = false;
        if (gneed) {
#pragma unroll
          for (int b = 0; b < 32; ++b) gbad |= (is_sent(gv[b]) != 0);
        }
        if (!(hbad || gbad)) break;
        spin_pause();
        if (gneed) {
#pragma unroll
          for (int b = 0; b < 32; ++b)
            if (is_sent(gv[b])) gv[b] = llc_load_async(gq + b * TT);
        }
        if (hbad) hv = llc_load4_async(hp);
        vm_wait0();
      }
      float ga = 0.f;
      if (gneed) {
#pragma unroll
        for (int b = 0; b < 32; ++b) ga += gv[b];   // same order as r5/r6
      }
      ((float4*)hfull)[tid] = hv;
      redG[hf][sF] = ga;                  // 0 for sF >= t (never read there)
    }
    __syncthreads();

    // [C1] matvec partials from REGISTER W (r6 order, bit-identical)
    float mp = 0.f;
    if (t >= 1) {
      const float4* hf4 = (const float4*)hfull;
#pragma unroll
      for (int i = 0; i < 16; ++i) {
        const int rb = (i << 6) + (qq << 2);
        const float4 hv = hf4[rb >> 2];
        mp += hv.x * w[i].x + hv.y * w[i].y + hv.z * w[i].z + hv.w * w[i].w;
      }
    }
    redM[qq][jj] = mp;

    // [F1] deferred reduce of step t-1: g_s, d_s, ||h||^2, Sigma d*g
    float dval = 0.f, gval = 0.f;
    if (t >= 1 && tid <= t - 1) {
      float g = redG[0][tid] + redG[1][tid];
      gval = g;
      if (tid < t - 1) { dval = cbuf[tid] * g; dbuf[tid] = dval; }
      else sHH = g;
    }
    float s1p = dval * gval;
    s1p += __shfl_xor(s1p, 1, 64);
    s1p += __shfl_xor(s1p, 2, 64);
    s1p += __shfl_xor(s1p, 4, 64);
    s1p += __shfl_xor(s1p, 8, 64);
    s1p += __shfl_xor(s1p, 16, 64);
    s1p += __shfl_xor(s1p, 32, 64);
    if (lane == 0) red2[wv] = s1p;
    __syncthreads();

    // [F2] c_{t-1}, z_{t-1}, e_{t-1}   +   [B] K[t-1] partials
    if (t >= 1) {
      if (tid == 0) {
        float s1 = red2[0] + red2[1] + red2[2] + red2[3];
        cbuf[t - 1] = 1.f / (1.f + sHH - s1);
      }
      if (wv == 0) {                      // z_{t-1} = -sum_{s<t-1} d_s e_s
        const int o = lane & 7, gr8 = lane >> 3;
        float zp = 0.f;
        for (int s = gr8; s < t - 1; s += 8) zp += dbuf[s] * Ebuf[s][o];
        zp += __shfl_xor(zp, 8, 64);
        zp += __shfl_xor(zp, 16, 64);
        zp += __shfl_xor(zp, 32, 64);
        if (lane < 8) {
          float z = -zp;
          zbuf[o] = z;
          Ebuf[t - 1][o] = z - Ybuf[t - 1][o];
          if (bid == 0) out[(t - 1) * ODIM + o] = z;
        }
      }
    }
    float kp = 0.f;
    if (t >= 2) {
      for (int s = qq; s < t - 1; s += 16) kp -= dbuf[s] * Ksl[s][jj];
    }
    redK[qq][jj] = kp;
    __syncthreads();

    // [C2] combine -> a_t, h_t; finalize K[t-1]; publish h (fire-and-forget)
    if (tid < JPB) {
      const int j = tid;
      if (t >= 1) {
        float kv = hfull[j0 + j];
#pragma unroll
        for (int q = 0; q < 16; ++q) kv += redK[q][j];
        Ksl[t - 1][j] = kv;
      }
      float acc = 0.f;
#pragma unroll
      for (int q = 0; q < 16; ++q) acc += redM[q][j];
      float fb = 0.f;
#pragma unroll
      for (int o = 0; o < ODIM; ++o) fb += zbuf[o] * Wfb_s[o][j];
      float a = 0.9f * abuf[j] + 0.1f * (acc + XW[t][j] + fb);
      abuf[j] = a;
      float h = tanhf(a);
      hcb[j] = h;
      AS(&ws->h[t][j0 + j], h);
    }
    __syncthreads();

    // [D] publish g-partials of step t (fire-and-forget, word = flag)
    if (tid <= t) {
      float gp = 0.f;
      if (tid < t) {
#pragma unroll
        for (int j = 0; j < JPB; ++j) gp += Ksl[tid][j] * hcb[j];
      } else {
#pragma unroll
        for (int j = 0; j < JPB; ++j) gp += hcb[j] * hcb[j];
      }
      AS(&ws->gpart[t][bid][tid], gp);
    }
    // no drain, no flag, no barrier — consumers validate per-word
  }

  // ---------------- epilogue: z_127 -> out[127] (bid 0 only) ----------------
  if (bid == 0) {
    float ga = 0.f;
    if (sF < TT - 1) {
      const float* gq = &ws->gpart[TT - 1][hf * 32][0] + sF;
      float gv[32];
#pragma unroll
      for (int b = 0; b < 32; ++b) gv[b] = AL(gq + b * TT);
      for (;;) {
        bool bad = false;
#pragma unroll
        for (int b = 0; b < 32; ++b) bad |= (__float_as_uint(gv[b]) == SENT);
        if (!bad) break;
        spin_pause();
#pragma unroll
        for (int b = 0; b < 32; ++b)
          if (__float_as_uint(gv[b]) == SENT) gv[b] = AL(gq + b * TT);
      }
#pragma unroll
      for (int b = 0; b < 32; ++b) ga += gv[b];
    }
    redG[hf][sF] = ga;
    __syncthreads();
    if (tid < TT - 1) dbuf[tid] = cbuf[tid] * (redG[0][tid] + redG[1][tid]);
    __syncthreads();
    if (wv == 0) {
      const int o = lane & 7, gr8 = lane >> 3;
      float zp = 0.f;
      for (int s = gr8; s < TT - 1; s += 8) zp += dbuf[s] * Ebuf[s][o];
      zp += __shfl_xor(zp, 8, 64);
      zp += __shfl_xor(zp, 16, 64);
      zp += __shfl_xor(zp, 32, 64);
      if (lane < 8) out[(TT - 1) * ODIM + o] = -zp;
    }
  }
}

extern "C" void kernel_launch(void* const* d_in, const int* in_sizes, int n_in,
                              void* d_out, int out_size, void* d_ws, size_t ws_size,
                              hipStream_t stream) {
  const float* x    = (const float*)d_in[0];
  const float* y    = (const float*)d_in[1];
  const float* Win  = (const float*)d_in[2];
  const float* Wrec = (const float*)d_in[3];
  const float* Wfb  = (const float*)d_in[4];
  // d_in[5] = wO (zeros), d_in[6] = P (identity): folded into implicit-P math.
  float* out = (float*)d_out;
  WS* ws = (WS*)d_ws;

  // Sentinel-fill the once-written dataflow buffers (0xFF bytes = NaN words).
  hipMemsetAsync(d_ws, 0xFF, sizeof(WS), stream);
  force_rls_kernel<<<NBLK, NTHR, 0, stream>>>(x, y, Win, Wrec, Wfb, out, ws);
}